// Round 4
// baseline (53.112 us; speedup 1.0000x reference)
//
#include <hip/hip_runtime.h>
#include <stdint.h>
#include <math.h>

// Problem constants (match reference)
#define B_N   32768
#define INDIM 256
#define HID   256
#define NE    8
#define KM1   4
#define KCLS  5
#define BM    64
#define PADN  (B_N + NE * BM)        // 33280
#define NBLK  (PADN / BM)            // 520 (divisible by 8 -> simple XCD swizzle)

typedef __bf16 bf16x8 __attribute__((ext_vector_type(8)));
typedef float  f32x4  __attribute__((ext_vector_type(4)));
typedef unsigned short u16x8 __attribute__((ext_vector_type(8)));

__device__ __forceinline__ unsigned short f2bf(float f) {
    union { float f; unsigned u; } v; v.f = f;
    unsigned r = v.u + 0x7FFFu + ((v.u >> 16) & 1u);   // RNE
    return (unsigned short)(r >> 16);
}
__device__ __forceinline__ float bf2f(unsigned short b) {
    union { unsigned u; float f; } v; v.u = ((unsigned)b) << 16;
    return v.f;
}

// ---- prep: W1 [E][IN][HID] f32 -> w1T [E][HID][IN] bf16; + zero hist/cursor, perm=-1 ----
__global__ __launch_bounds__(256) void k_w1t(const float* __restrict__ W1,
                                             unsigned short* __restrict__ w1T,
                                             int* __restrict__ perm,
                                             int* __restrict__ hist,
                                             int* __restrict__ cursor) {
    int gid = blockIdx.x * 256 + threadIdx.x;          // 0..32767
    perm[gid] = -1;
    if (gid + 32768 < PADN) perm[gid + 32768] = -1;
    if (gid < NE) { hist[gid] = 0; cursor[gid] = 0; }

    __shared__ float tile[64][65];
    int b  = blockIdx.x;            // E*4*4 = 128 blocks
    int e  = b >> 4;
    int ti = (b >> 2) & 3;          // i (K) tile
    int th = b & 3;                 // h (N) tile
    const float* src = W1 + (((size_t)e * INDIM) + (size_t)ti * 64) * HID + th * 64;
    int col = threadIdx.x & 63;
    int r0  = (threadIdx.x >> 6) * 16;
    #pragma unroll
    for (int rr = 0; rr < 16; ++rr)
        tile[r0 + rr][col] = src[(size_t)(r0 + rr) * HID + col];
    __syncthreads();
    int hl = threadIdx.x >> 2;      // 0..63  (h within tile)
    int iq = threadIdx.x & 3;       // quarter of i range
    unsigned short* dst = w1T + (((size_t)e * HID) + th * 64 + hl) * INDIM + ti * 64 + iq * 16;
    #pragma unroll
    for (int s = 0; s < 16; ++s)
        dst[s] = f2bf(tile[iq * 16 + s][hl]);
}

// ---- prep: histogram (ballot-based, no same-address LDS atomic storm) ----
__global__ __launch_bounds__(256) void k_hist(const int* __restrict__ sidx,
                                              int* __restrict__ hist) {
    __shared__ int lh[NE];
    if (threadIdx.x < NE) lh[threadIdx.x] = 0;
    __syncthreads();
    int i = blockIdx.x * 256 + threadIdx.x;            // exactly B_N threads
    int e = sidx[i];
    int lane = threadIdx.x & 63;
    #pragma unroll
    for (int t = 0; t < NE; ++t) {
        unsigned long long m = __ballot(e == t);
        if (lane == t) atomicAdd(&lh[t], (int)__popcll(m));
    }
    __syncthreads();
    if (threadIdx.x < NE) atomicAdd(&hist[threadIdx.x], lh[threadIdx.x]);
}

// ---- prep: scatter into per-expert segments (offs recomputed from hist in-block) ----
__global__ __launch_bounds__(256) void k_scatter(const int* __restrict__ sidx,
                                                 const int* __restrict__ hist,
                                                 int* __restrict__ cursor,
                                                 int* __restrict__ perm) {
    __shared__ int lcnt[NE];
    __shared__ int wbase[4][NE];
    __shared__ int gbase[NE];
    if (threadIdx.x < NE) lcnt[threadIdx.x] = 0;
    __syncthreads();
    int i = blockIdx.x * 256 + threadIdx.x;
    int e = sidx[i];
    int lane = threadIdx.x & 63;
    int wave = threadIdx.x >> 6;
    int posw = 0;
    #pragma unroll
    for (int t = 0; t < NE; ++t) {
        unsigned long long m = __ballot(e == t);
        if (e == t) posw = (int)__popcll(m & ((1ull << lane) - 1ull));
        if (lane == t) wbase[wave][t] = atomicAdd(&lcnt[t], (int)__popcll(m));
    }
    __syncthreads();
    if (threadIdx.x < NE)
        gbase[threadIdx.x] = atomicAdd(&cursor[threadIdx.x], lcnt[threadIdx.x]);
    __syncthreads();
    int off = 0;
    #pragma unroll
    for (int t = 0; t < NE; ++t)
        off += (t < e) ? (((hist[t] + 63) >> 6) << 6) : 0;
    perm[off + gbase[e] + wbase[wave][e] + posw] = i;
}

__device__ __forceinline__ void gload_lds16(const void* g, void* l) {
    __builtin_amdgcn_global_load_lds(
        (__attribute__((address_space(1))) unsigned int*)(g),
        (__attribute__((address_space(3))) unsigned int*)(l),
        16, 0, 0);
}

// ---- main: fused grouped GEMM (bf16 MFMA) + bias/relu + layer2 + ordinal probs ----
__global__ __launch_bounds__(256) void k_main(
    const float* __restrict__ x,  const float* __restrict__ b1,
    const float* __restrict__ W2, const float* __restrict__ b2,
    const unsigned short* __restrict__ w1T,
    const int* __restrict__ perm, const int* __restrict__ hist,
    float* __restrict__ out)
{
    __shared__ unsigned short xs[BM * 256];        // 32KB, swizzled; reused for h
    __shared__ unsigned short w1s[2][256 * 32];    // 2x16KB W1 K-slices
    __shared__ float w2s[1040];                    // W2[e] bank-padded: idx = k*4+kk+(k>>6)*4

    // XCD-aware swizzle (520 % 8 == 0 -> contiguous 65-block chunks per XCD)
    int bid  = (blockIdx.x & 7) * (NBLK / 8) + (blockIdx.x >> 3);
    int base = bid * BM;

    // expert lookup from hist (uniform scalar loads + tiny scan)
    int total = 0, e = 0;
    #pragma unroll
    for (int t = 0; t < NE; ++t) {
        int start = total;
        total += ((hist[t] + 63) >> 6) << 6;
        if (base >= start) e = t;
    }
    if (base >= total) return;

    int tid  = threadIdx.x;
    int lane = tid & 63;
    int wave = tid >> 6;
    int r15  = lane & 15;
    int hi   = lane >> 4;

    // ---- stage gathered x rows -> LDS bf16 (16B-chunk XOR swizzle: chunk ^= row&7) ----
    int row = tid >> 2;          // 0..63
    int q   = tid & 3;           // quarter of 256 cols / later: k-range & logit idx
    int smp = perm[base + row];
    {
        const float* xr = x + (size_t)(smp < 0 ? 0 : smp) * INDIM + q * 64;
        #pragma unroll
        for (int cc = 0; cc < 8; ++cc) {
            int clin = q * 8 + cc;
            int csw  = clin ^ (row & 7);
            u16x8 v = {0, 0, 0, 0, 0, 0, 0, 0};
            if (smp >= 0) {
                const f32x4* p4 = (const f32x4*)(xr + cc * 8);
                f32x4 a0 = __builtin_nontemporal_load(p4);       // x is read-once
                f32x4 a1 = __builtin_nontemporal_load(p4 + 1);
                v[0] = f2bf(a0[0]); v[1] = f2bf(a0[1]); v[2] = f2bf(a0[2]); v[3] = f2bf(a0[3]);
                v[4] = f2bf(a1[0]); v[5] = f2bf(a1[1]); v[6] = f2bf(a1[2]); v[7] = f2bf(a1[3]);
            }
            *(u16x8*)&xs[row * 256 + (csw << 3)] = v;
        }
    }
    const float* w2e = W2 + (size_t)e * HID * KM1;
    {   // stage W2[e] (4KB) -> LDS, padded so epilogue reads are 4-slot broadcast
        f32x4 wv = *(const f32x4*)(w2e + (size_t)tid * 4);
        *(f32x4*)&w2s[tid * 4 + (tid >> 6) * 4] = wv;
    }

    const unsigned short* w1e = w1T + (size_t)e * HID * INDIM;
    auto stage_w1 = [&](int buf, int ks) {
        #pragma unroll
        for (int i = 0; i < 4; ++i) {
            int nb = wave * 4 + i;
            const unsigned short* g = w1e
                + ((size_t)(nb * 16 + (lane >> 2))) * INDIM + ks * 32 + (lane & 3) * 8;
            unsigned short* l = &w1s[buf][nb * 16 * 32];
            gload_lds16(g, l);
        }
    };

    stage_w1(0, 0);
    __syncthreads();

    f32x4 acc[4][4];
    #pragma unroll
    for (int mi = 0; mi < 4; ++mi)
        #pragma unroll
        for (int ni = 0; ni < 4; ++ni) {
            f32x4 z = {0.f, 0.f, 0.f, 0.f};
            acc[mi][ni] = z;
        }

    #pragma unroll
    for (int ks = 0; ks < 8; ++ks) {
        int cur = ks & 1;
        if (ks < 7) stage_w1(cur ^ 1, ks + 1);
        bf16x8 af[4], bfr[4];
        #pragma unroll
        for (int mi = 0; mi < 4; ++mi) {
            int r  = mi * 16 + r15;
            int cc = ks * 4 + hi;
            af[mi] = *(const bf16x8*)&xs[r * 256 + ((cc ^ (r & 7)) << 3)];
        }
        #pragma unroll
        for (int ni = 0; ni < 4; ++ni) {
            int n = wave * 64 + ni * 16 + r15;
            bfr[ni] = *(const bf16x8*)&w1s[cur][n * 32 + hi * 8];
        }
        #pragma unroll
        for (int mi = 0; mi < 4; ++mi)
            #pragma unroll
            for (int ni = 0; ni < 4; ++ni)
                acc[mi][ni] = __builtin_amdgcn_mfma_f32_16x16x32_bf16(
                    af[mi], bfr[ni], acc[mi][ni], 0, 0, 0);
        __syncthreads();
    }

    // ---- h = relu(acc + b1) -> xs (bf16, same swizzle) ----
    float b1v[4];
    #pragma unroll
    for (int ni = 0; ni < 4; ++ni)
        b1v[ni] = b1[e * HID + wave * 64 + ni * 16 + r15];
    #pragma unroll
    for (int mi = 0; mi < 4; ++mi) {
        #pragma unroll
        for (int ni = 0; ni < 4; ++ni) {
            int colg = wave * 64 + ni * 16 + r15;
            #pragma unroll
            for (int j = 0; j < 4; ++j) {
                int rowg = mi * 16 + hi * 4 + j;
                float h = fmaxf(acc[mi][ni][j] + b1v[ni], 0.f);
                xs[rowg * 256 + (((colg >> 3) ^ (rowg & 7)) << 3) + (colg & 7)] = f2bf(h);
            }
        }
    }
    __syncthreads();

    // ---- layer 2: split-K across the 4-thread quad, W2 from LDS ----
    f32x4 lac = {0.f, 0.f, 0.f, 0.f};
    #pragma unroll
    for (int s = 0; s < 8; ++s) {
        int c = q * 8 + s;
        u16x8 hv = *(const u16x8*)&xs[row * 256 + ((c ^ (row & 7)) << 3)];
        #pragma unroll
        for (int j = 0; j < 8; ++j) {
            int k = c * 8 + j;
            float hf = bf2f(hv[j]);
            const f32x4 wv = *(const f32x4*)&w2s[k * 4 + (k >> 6) * 4];
            lac[0] += hf * wv[0]; lac[1] += hf * wv[1];
            lac[2] += hf * wv[2]; lac[3] += hf * wv[3];
        }
    }
    #pragma unroll
    for (int c4 = 0; c4 < 4; ++c4) {
        lac[c4] += __shfl_xor(lac[c4], 1, 4);
        lac[c4] += __shfl_xor(lac[c4], 2, 4);
    }

    if (smp >= 0) {
        const float* b2e = b2 + e * KM1;
        float l0 = lac[0] + b2e[0], l1 = lac[1] + b2e[1];
        float l2 = lac[2] + b2e[2], l3 = lac[3] + b2e[3];
        float q0 = 1.f / (1.f + expf(-l0)), q1 = 1.f / (1.f + expf(-l1));
        float q2 = 1.f / (1.f + expf(-l2)), q3 = 1.f / (1.f + expf(-l3));
        float p0 = fmaxf(1.f - q0, 1e-8f), p1 = fmaxf(q0 - q1, 1e-8f);
        float p2 = fmaxf(q1 - q2, 1e-8f), p3 = fmaxf(q2 - q3, 1e-8f);
        float p4 = fmaxf(q3, 1e-8f);
        float inv = 1.f / (p0 + p1 + p2 + p3 + p4);
        // static-index component pick (avoid runtime-indexed array -> scratch)
        float myl = (q & 1) ? ((q & 2) ? l3 : l1) : ((q & 2) ? l2 : l0);
        float myp = (q & 1) ? ((q & 2) ? p3 : p1) : ((q & 2) ? p2 : p0);
        out[(size_t)smp * KM1 + q] = myl;
        float* probs = out + (size_t)B_N * KM1;
        probs[(size_t)smp * KCLS + q] = myp * inv;
        if (q == 3) probs[(size_t)smp * KCLS + 4] = p4 * inv;
    }
}

extern "C" void kernel_launch(void* const* d_in, const int* in_sizes, int n_in,
                              void* d_out, int out_size, void* d_ws, size_t ws_size,
                              hipStream_t stream) {
    const float* x   = (const float*)d_in[0];
    const int*   sid = (const int*)d_in[1];
    const float* W1  = (const float*)d_in[2];
    const float* b1  = (const float*)d_in[3];
    const float* W2  = (const float*)d_in[4];
    const float* b2  = (const float*)d_in[5];
    float* out = (float*)d_out;

    char* ws = (char*)d_ws;
    unsigned short* w1T = (unsigned short*)ws;             // 1048576 B
    int* perm   = (int*)(ws + 1048576);                    // 133120 B
    int* hist   = (int*)(ws + 1048576 + 133120);           // 32 B
    int* cursor = (int*)(ws + 1048576 + 133152);           // 32 B

    k_w1t    <<<dim3(128),  dim3(256), 0, stream>>>(W1, w1T, perm, hist, cursor);
    k_hist   <<<dim3(128),  dim3(256), 0, stream>>>(sid, hist);
    k_scatter<<<dim3(128),  dim3(256), 0, stream>>>(sid, hist, cursor, perm);
    k_main   <<<dim3(NBLK), dim3(256), 0, stream>>>(x, b1, W2, b2, w1T, perm, hist, out);
}

// Round 5
// 33.831 us; speedup vs baseline: 1.5699x; 1.5699x over previous
//
#include <hip/hip_runtime.h>
#include <stdint.h>
#include <math.h>

// Problem constants (match reference)
#define B_N   32768
#define INDIM 256
#define HID   256
#define NE    8
#define KM1   4
#define KCLS  5
#define BM    64
#define NBLK  ((B_N + NE * BM) / BM)   // 520 blocks (max padded segments)

typedef __bf16 bf16x8 __attribute__((ext_vector_type(8)));
typedef float  f32x4  __attribute__((ext_vector_type(4)));
typedef unsigned short u16x8 __attribute__((ext_vector_type(8)));

__device__ __forceinline__ unsigned short f2bf(float f) {
    union { float f; unsigned u; } v; v.f = f;
    unsigned r = v.u + 0x7FFFu + ((v.u >> 16) & 1u);   // RNE
    return (unsigned short)(r >> 16);
}
__device__ __forceinline__ float bf2f(unsigned short b) {
    union { unsigned u; float f; } v; v.u = ((unsigned)b) << 16;
    return v.f;
}
// xs swizzle: chunk-of-8-bf16 swizzled so both row and chunk bits hit banks
__device__ __forceinline__ int SWZ(int r, int c) {
    return c ^ ((r & 7) << 2) ^ ((r >> 3) & 3);
}

// ---- prep 1: W1 [E][IN][HID] f32 -> w1p packed MFMA-B fragment order bf16
//      w1p[e][ks][nb][lane][8] = W1[e][ks*32+(lane>>4)*8+j][nb*16+(lane&15)]
//      Also: per-block expert histogram part[128][8] (plain stores, no atomics).
__global__ __launch_bounds__(256) void k_w1t(const float* __restrict__ W1,
                                             const int* __restrict__ sidx,
                                             unsigned short* __restrict__ w1p,
                                             int* __restrict__ part) {
    __shared__ float tile[64][65];
    __shared__ int wc[4][NE];
    int t    = threadIdx.x;
    int b    = blockIdx.x;          // 128 blocks
    int lane = t & 63;
    int wave = t >> 6;

    // per-block expert histogram via ballot (256 samples per block)
    int i = b * 256 + t;
    int es = sidx[i];
    #pragma unroll
    for (int t2 = 0; t2 < NE; ++t2) {
        unsigned long long m = __ballot(es == t2);
        if (lane == t2) wc[wave][t2] = (int)__popcll(m);
    }

    int e  = b >> 4;
    int ti = (b >> 2) & 3;          // k-tile (64 k's = ks pair)
    int th = b & 3;                 // n-tile (64 n's = 4 nb's)
    const float* src = W1 + (((size_t)e * INDIM) + (size_t)ti * 64) * HID + th * 64;
    int col = t & 63;
    int r0  = (t >> 6) * 16;
    #pragma unroll
    for (int rr = 0; rr < 16; ++rr)
        tile[r0 + rr][col] = src[(size_t)(r0 + rr) * HID + col];
    __syncthreads();

    if (t < NE) part[b * NE + t] = wc[0][t] + wc[1][t] + wc[2][t] + wc[3][t];

    int u = t >> 6;                 // which nb of the 4 in this n-tile
    #pragma unroll
    for (int ks2 = 0; ks2 < 2; ++ks2) {
        int ks = ti * 2 + ks2;
        int nb = th * 4 + u;
        u16x8 v;
        #pragma unroll
        for (int j = 0; j < 8; ++j)
            v[j] = f2bf(tile[ks2 * 32 + (lane >> 4) * 8 + j][u * 16 + (lane & 15)]);
        *(u16x8*)&w1p[((((size_t)e * 8 + ks) * 16 + nb) * 64 + lane) * 8] = v;
    }
}

// ---- prep 2: deterministic rank scatter (prefix over per-block partials) ----
__global__ __launch_bounds__(256) void k_scatter(const int* __restrict__ sidx,
                                                 const int* __restrict__ part,
                                                 int* __restrict__ perm,
                                                 int* __restrict__ meta) {
    __shared__ int pp[128][NE];
    __shared__ int pre8[NE], tot8[NE];
    __shared__ int wc[4][NE];
    int t    = threadIdx.x;
    int b    = blockIdx.x;
    int lane = t & 63;
    int wave = t >> 6;

    if (t < 128) {
        #pragma unroll
        for (int e2 = 0; e2 < NE; ++e2) pp[t][e2] = part[t * NE + e2];
    }
    int i = b * 256 + t;
    int e = sidx[i];
    int posw = 0;
    #pragma unroll
    for (int t2 = 0; t2 < NE; ++t2) {
        unsigned long long m = __ballot(e == t2);
        if (e == t2) posw = (int)__popcll(m & ((1ull << lane) - 1ull));
        if (lane == t2) wc[wave][t2] = (int)__popcll(m);
    }
    __syncthreads();
    if (t < NE) {
        int s = 0, a = 0;
        for (int b2 = 0; b2 < 128; ++b2) {
            int v = pp[b2][t];
            if (b2 < b) s += v;
            a += v;
        }
        pre8[t] = s; tot8[t] = a;
        meta[t] = a;                       // same value from every block: benign
    }
    __syncthreads();
    int off = 0;
    #pragma unroll
    for (int t2 = 0; t2 < NE; ++t2)
        off += (t2 < e) ? (((tot8[t2] + 63) >> 6) << 6) : 0;
    int wsum = 0;
    #pragma unroll
    for (int w2 = 0; w2 < 4; ++w2)
        wsum += (w2 < wave) ? wc[w2][e] : 0;
    perm[off + pre8[e] + wsum + posw] = i;
}

// ---- main: grouped GEMM, B direct-from-L2 (packed), no K-loop barriers ----
__global__ __launch_bounds__(256, 3) void k_main(
    const float* __restrict__ x,  const float* __restrict__ b1,
    const float* __restrict__ W2, const float* __restrict__ b2,
    const unsigned short* __restrict__ w1p,
    const int* __restrict__ perm, const int* __restrict__ meta,
    float* __restrict__ out)
{
    __shared__ unsigned short xs[BM * 256];   // 32KB x tile (SWZ), reused for h
    __shared__ float w2s[1040];               // W2[e] bank-padded

    int base = blockIdx.x * BM;
    // expert lookup from meta counts (uniform; no runtime-indexed local array)
    int e = 0, segstart = 0, segcnt = 0, acc_off = 0;
    #pragma unroll
    for (int t = 0; t < NE; ++t) {
        int c  = meta[t];
        int st = acc_off;
        acc_off += ((c + 63) >> 6) << 6;
        if (base >= st) { e = t; segstart = st; segcnt = c; }
    }
    if (base >= acc_off) return;
    int segend = segstart + segcnt;

    int tid  = threadIdx.x;
    int lane = tid & 63;
    int wave = tid >> 6;
    int r15  = lane & 15;
    int hi   = lane >> 4;

    // ---- stage gathered x rows -> LDS bf16 (SWZ) ----
    {
        int row  = tid & 63;
        int q    = tid >> 6;
        int prow = base + row;
        int smp  = (prow < segend) ? perm[prow] : -1;
        const float* xr = x + (size_t)(smp < 0 ? 0 : smp) * INDIM + q * 64;
        #pragma unroll
        for (int cc = 0; cc < 8; ++cc) {
            int csw = SWZ(row, q * 8 + cc);
            u16x8 v = {0, 0, 0, 0, 0, 0, 0, 0};
            if (smp >= 0) {
                const f32x4* p4 = (const f32x4*)(xr + cc * 8);
                f32x4 a0 = p4[0], a1 = p4[1];
                v[0] = f2bf(a0[0]); v[1] = f2bf(a0[1]); v[2] = f2bf(a0[2]); v[3] = f2bf(a0[3]);
                v[4] = f2bf(a1[0]); v[5] = f2bf(a1[1]); v[6] = f2bf(a1[2]); v[7] = f2bf(a1[3]);
            }
            *(u16x8*)&xs[row * 256 + (csw << 3)] = v;
        }
    }
    {   // stage W2[e] (4KB) -> LDS, padded for broadcast reads
        const float* w2e = W2 + (size_t)e * HID * KM1;
        f32x4 wv = *(const f32x4*)(w2e + (size_t)tid * 4);
        *(f32x4*)&w2s[tid * 4 + (tid >> 6) * 4] = wv;
    }
    __syncthreads();   // xs + w2s ready; ONLY barrier before epilogue

    const unsigned short* w1pe = w1p + (size_t)e * (8 * 16 * 64 * 8);
    auto loadB = [&](int ks, int ni) -> bf16x8 {
        return *(const bf16x8*)&w1pe[(((ks * 16 + wave * 4 + ni) * 64) + lane) * 8];
    };

    f32x4 acc[4][4];
    #pragma unroll
    for (int mi = 0; mi < 4; ++mi)
        #pragma unroll
        for (int ni = 0; ni < 4; ++ni) {
            f32x4 z = {0.f, 0.f, 0.f, 0.f};
            acc[mi][ni] = z;
        }

    bf16x8 bcur[4];
    #pragma unroll
    for (int ni = 0; ni < 4; ++ni) bcur[ni] = loadB(0, ni);

    #pragma unroll
    for (int ks = 0; ks < 8; ++ks) {
        bf16x8 bnext[4];
        if (ks < 7) {
            #pragma unroll
            for (int ni = 0; ni < 4; ++ni) bnext[ni] = loadB(ks + 1, ni);
        }
        bf16x8 af[4];
        #pragma unroll
        for (int mi = 0; mi < 4; ++mi) {
            int r = mi * 16 + r15;
            af[mi] = *(const bf16x8*)&xs[r * 256 + (SWZ(r, ks * 4 + hi) << 3)];
        }
        #pragma unroll
        for (int mi = 0; mi < 4; ++mi)
            #pragma unroll
            for (int ni = 0; ni < 4; ++ni)
                acc[mi][ni] = __builtin_amdgcn_mfma_f32_16x16x32_bf16(
                    af[mi], bcur[ni], acc[mi][ni], 0, 0, 0);
        if (ks < 7) {
            #pragma unroll
            for (int ni = 0; ni < 4; ++ni) bcur[ni] = bnext[ni];
        }
    }
    __syncthreads();   // all xs reads done before h overwrite

    // ---- h = relu(acc + b1) -> xs (bf16, SWZ) ----
    float b1v[4];
    #pragma unroll
    for (int ni = 0; ni < 4; ++ni)
        b1v[ni] = b1[e * HID + wave * 64 + ni * 16 + r15];
    #pragma unroll
    for (int mi = 0; mi < 4; ++mi) {
        #pragma unroll
        for (int ni = 0; ni < 4; ++ni) {
            int colg  = wave * 64 + ni * 16 + r15;
            int chunk = colg >> 3;
            #pragma unroll
            for (int j = 0; j < 4; ++j) {
                int rowg = mi * 16 + hi * 4 + j;
                float h = fmaxf(acc[mi][ni][j] + b1v[ni], 0.f);
                xs[rowg * 256 + (SWZ(rowg, chunk) << 3) + (colg & 7)] = f2bf(h);
            }
        }
    }
    __syncthreads();

    // ---- layer 2: split-K across quad, W2 from LDS ----
    int row2 = tid >> 2;
    int q2   = tid & 3;
    f32x4 lac = {0.f, 0.f, 0.f, 0.f};
    #pragma unroll
    for (int s = 0; s < 8; ++s) {
        int c = q2 * 8 + s;
        u16x8 hv = *(const u16x8*)&xs[row2 * 256 + (SWZ(row2, c) << 3)];
        #pragma unroll
        for (int j = 0; j < 8; ++j) {
            int k = c * 8 + j;
            float hf = bf2f(hv[j]);
            const f32x4 wv = *(const f32x4*)&w2s[k * 4 + (k >> 6) * 4];
            lac[0] += hf * wv[0]; lac[1] += hf * wv[1];
            lac[2] += hf * wv[2]; lac[3] += hf * wv[3];
        }
    }
    #pragma unroll
    for (int c4 = 0; c4 < 4; ++c4) {
        lac[c4] += __shfl_xor(lac[c4], 1, 4);
        lac[c4] += __shfl_xor(lac[c4], 2, 4);
    }

    if (base + row2 < segend) {
        int smp = perm[base + row2];
        const float* b2e = b2 + e * KM1;
        float l0 = lac[0] + b2e[0], l1 = lac[1] + b2e[1];
        float l2 = lac[2] + b2e[2], l3 = lac[3] + b2e[3];
        float q0 = 1.f / (1.f + expf(-l0)), q1 = 1.f / (1.f + expf(-l1));
        float q2v = 1.f / (1.f + expf(-l2)), q3 = 1.f / (1.f + expf(-l3));
        float p0 = fmaxf(1.f - q0, 1e-8f), p1 = fmaxf(q0 - q1, 1e-8f);
        float p2 = fmaxf(q1 - q2v, 1e-8f), p3 = fmaxf(q2v - q3, 1e-8f);
        float p4 = fmaxf(q3, 1e-8f);
        float inv = 1.f / (p0 + p1 + p2 + p3 + p4);
        float myl = (q2 & 1) ? ((q2 & 2) ? l3 : l1) : ((q2 & 2) ? l2 : l0);
        float myp = (q2 & 1) ? ((q2 & 2) ? p3 : p1) : ((q2 & 2) ? p2 : p0);
        out[(size_t)smp * KM1 + q2] = myl;
        float* probs = out + (size_t)B_N * KM1;
        probs[(size_t)smp * KCLS + q2] = myp * inv;
        if (q2 == 3) probs[(size_t)smp * KCLS + 4] = p4 * inv;
    }
}

extern "C" void kernel_launch(void* const* d_in, const int* in_sizes, int n_in,
                              void* d_out, int out_size, void* d_ws, size_t ws_size,
                              hipStream_t stream) {
    const float* x   = (const float*)d_in[0];
    const int*   sid = (const int*)d_in[1];
    const float* W1  = (const float*)d_in[2];
    const float* b1  = (const float*)d_in[3];
    const float* W2  = (const float*)d_in[4];
    const float* b2  = (const float*)d_in[5];
    float* out = (float*)d_out;

    char* ws = (char*)d_ws;
    unsigned short* w1p = (unsigned short*)ws;             // 1048576 B
    int* perm = (int*)(ws + 1048576);                      // 133120 B
    int* part = (int*)(ws + 1048576 + 133120);             // 128*8*4 = 4096 B
    int* meta = (int*)(ws + 1048576 + 133120 + 4096);      // 32 B

    k_w1t    <<<dim3(128),  dim3(256), 0, stream>>>(W1, sid, w1p, part);
    k_scatter<<<dim3(128),  dim3(256), 0, stream>>>(sid, part, perm, meta);
    k_main   <<<dim3(NBLK), dim3(256), 0, stream>>>(x, b1, W2, b2, w1p, perm, meta, out);
}